// Round 12
// baseline (777.181 us; speedup 1.0000x reference)
//
#include <hip/hip_runtime.h>
#include <hip/hip_bf16.h>
#include <stdint.h>

typedef __bf16 bf16_t;
typedef bf16_t bf16x8 __attribute__((ext_vector_type(8)));
typedef bf16_t bf16x4 __attribute__((ext_vector_type(4)));
typedef float  f32x4  __attribute__((ext_vector_type(4)));

#define AS1(p) ((const __attribute__((address_space(1))) void*)(p))
#define AS3(p) ((__attribute__((address_space(3))) void*)(p))

static constexpr int B_ = 32, S_ = 1024, D_ = 1024, P_ = 4, F_ = 4096;
static constexpr int SPP = S_ / P_;          // 256 rows per (batch, phase) chunk
static constexpr int MP  = B_ * SPP;         // 8192 rows per phase-group

// ---- x: [B,S,D] f32 -> xg: [P][MP][D] bf16 (phase-grouped, contiguous) ----
__global__ void conv_x_kernel(const float* __restrict__ x, bf16_t* __restrict__ xg) {
  const int64_t n4 = (int64_t)B_ * S_ * D_ / 4;
  for (int64_t i = (int64_t)blockIdx.x * blockDim.x + threadIdx.x; i < n4;
       i += (int64_t)gridDim.x * blockDim.x) {
    int64_t e = i << 2;
    int d = (int)(e & (D_ - 1));
    int s = (int)((e >> 10) & (S_ - 1));
    int b = (int)(e >> 20);
    int p = s >> 8;
    int r = (b << 8) | (s & 255);
    const float4 v = ((const float4*)x)[i];
    bf16x4 o;
    o[0] = (bf16_t)v.x; o[1] = (bf16_t)v.y; o[2] = (bf16_t)v.z; o[3] = (bf16_t)v.w;
    *(bf16x4*)&xg[(((int64_t)p * MP + r) << 10) | d] = o;
  }
}

// ---- W: [P][K][N] f32 -> Wt: [P][N][K] bf16 (LDS-tiled transpose) ----
__global__ void conv_wt_kernel(const float* __restrict__ W, bf16_t* __restrict__ Wt,
                               int K, int N) {
  __shared__ bf16_t tile[32][33];
  const int p = blockIdx.z;
  const float* Wp = W + (int64_t)p * K * N;
  bf16_t* Wtp = Wt + (int64_t)p * K * N;
  const int n0 = blockIdx.x * 32, k0 = blockIdx.y * 32;
  const int tx = threadIdx.x & 31, ty = threadIdx.x >> 5;
  #pragma unroll
  for (int j = 0; j < 4; ++j) {
    int kr = ty + j * 8;
    tile[kr][tx] = (bf16_t)Wp[(int64_t)(k0 + kr) * N + n0 + tx];
  }
  __syncthreads();
  #pragma unroll
  for (int j = 0; j < 4; ++j) {
    int nr = ty + j * 8;
    Wtp[(int64_t)(n0 + nr) * K + k0 + tx] = tile[tx][nr];
  }
}

// ====== 256x256 GEMM — B from global-to-reg, A-only LDS (R12) ======
// C[M,N] = A[M,K] * Bt[N,K]^T (+bias, opt ReLU). BM=BN=256, BK=64, 8 waves.
// LDS 64 KiB: At0/At1 only (256x64 bf16 each), double-buffered per K-tile.
// A swizzle unchanged: (row,cb) at row*128 + (cb^((row&7)<<4)); gload_lds
// dest LINEAR, inverse perm on global source.
// B-fragments are k-contiguous 16B/lane -> loaded DIRECTLY from global (L2)
// into VGPRs, no LDS staging. DS traffic/K-tile drops ~2300 -> ~1540 cy/CU
// (A reads 128 x b128 + A stage writes), below the 2483 cy MFMA floor.
// B(t+1) loads REUSE b0/b1 regs after their last consumer ISSUES (in-order
// issue; HK T16 time-share) -> no VGPR growth (~130 VGPR + 128 AGPR acc).
//
// Per K-tile (1 barrier; quad order frees b0 after Q3, b1 after Q4):
//   [stage A(t+1)->buf^1: 4 gload_lds] SBAR
//   a0 reads(8) | Q1(a0,b0) SBAR | a1 reads(8) | Q3(a1,b0) SBAR
//   [b0 <- B(t+1): 4 global] SBAR | Q2(a0,b1) SBAR | Q4(a1,b1)
//   [b1 <- B(t+1): 4 global] | VMCNT8 (FIFO [stage4,B0,B1] -> retires stage)
//   SBAR BAR
// RAW(staged A): vmcnt(8)+BAR before next tile's a-reads. WAR(buf^1): its
// last reads were tile t-1's, lgkm-complete before t-1's Q3/Q4 issue < the
// t-1 end barrier < this stage. b-frag RAW: compiler-tracked (plain loads).

__device__ __forceinline__ bf16x8 ldsfrag(const char* region, int row, int cb) {
  return *(const bf16x8*)(region + row * 128 + (cb ^ ((row & 7) << 4)));
}

template<int LDK>
__device__ __forceinline__ void stage_half(const bf16_t* gsrc, char* ldsreg, int t) {
  #pragma unroll
  for (int j = 0; j < 2; ++j) {
    const int idx = j * 512 + t;          // 1024 x 16B = 128 rows x 64 cols bf16
    const int row = idx >> 3;
    const int cb  = ((idx & 7) << 4) ^ ((row & 7) << 4);   // inverse-swizzled src col
    __builtin_amdgcn_global_load_lds(AS1((const char*)(gsrc + (int64_t)row * LDK) + cb),
                                     AS3(ldsreg + idx * 16), 16, 0, 0);
  }
}

#define MFMA_QUAD(AF, BF, MO, NO) \
  do { _Pragma("unroll") for (int m_ = 0; m_ < 4; ++m_) \
       _Pragma("unroll") for (int n_ = 0; n_ < 2; ++n_) \
       _Pragma("unroll") for (int k_ = 0; k_ < 2; ++k_) \
         acc[(MO) + m_][(NO) + n_] = __builtin_amdgcn_mfma_f32_16x16x32_bf16( \
             AF[m_][k_], BF[n_][k_], acc[(MO) + m_][(NO) + n_], 0, 0, 0); } while (0)

// A fragment reads: base pointer + compile-time immediate (R10 form)
#define FRAG_A(DST, BUF, MO) \
  do { _Pragma("unroll") for (int m_ = 0; m_ < 4; ++m_) { \
         DST[m_][0] = *(const bf16x8*)(baseA_k0 + (BUF) * 32768 + ((MO) + m_) * 2048); \
         DST[m_][1] = *(const bf16x8*)(baseA_k1 + (BUF) * 32768 + ((MO) + m_) * 2048); } } while (0)

// B fragment loads straight from global: frag(n,ks) covers k = K0+ks*32+hi*8..+8
#define LOAD_B(DST, K0, NO) \
  do { _Pragma("unroll") for (int n_ = 0; n_ < 2; ++n_) \
       _Pragma("unroll") for (int ks_ = 0; ks_ < 2; ++ks_) \
         DST[n_][ks_] = *(const bf16x8*)(Bt_th + ((NO) + n_) * 16 * KK + (K0) + ks_ * 32); } while (0)

#define BAR()   __builtin_amdgcn_s_barrier()
#define SBAR()  __builtin_amdgcn_sched_barrier(0)
#define PRIO(x) __builtin_amdgcn_s_setprio(x)
#define VMCNT8() asm volatile("s_waitcnt vmcnt(8)" ::: "memory")
#define VMCNT0() asm volatile("s_waitcnt vmcnt(0)" ::: "memory")

template<bool RELU, bool OUT_BF16, int KK, int NN>
__global__ __launch_bounds__(512, 2)
void ffgemm8_kernel(const bf16_t* __restrict__ A, const bf16_t* __restrict__ Bt,
                    const float* __restrict__ bias, void* __restrict__ outv, int M) {
  static_assert(KK % 128 == 0, "need even number of 64-wide K tiles");
  __shared__ __align__(16) char smem[65536];   // A only: At0 [0,32K), At1 [32K,64K)
  char* const At0 = smem;

  const int t = threadIdx.x, lane = t & 63, w = t >> 6;
  const int wm = w >> 2, wn = w & 3;          // 2M x 4N wave grid
  const int fr = lane & 15, hi = lane >> 4;

  // precomputed per-thread LDS A-fragment base pointers (row&7 == fr&7)
  const int xorm = (fr & 7) << 4;
  const char* const baseA_k0 = At0 + (wm * 128 + fr) * 128 + ((hi * 16) ^ xorm);
  const char* const baseA_k1 = At0 + (wm * 128 + fr) * 128 + ((64 + hi * 16) ^ xorm);

  // T1: bijective XCD swizzle (nwg % 8 == 0) + 4-row supertile banding for L2
  const int gx = gridDim.x, gy = gridDim.y;
  const int nwg = gx * gy * (int)gridDim.z;
  const int id  = ((int)blockIdx.z * gy + (int)blockIdx.y) * gx + (int)blockIdx.x;
  const int swz = (id & 7) * (nwg >> 3) + (id >> 3);
  const int per_p = gx * gy;
  const int p  = swz / per_p;
  const int q  = swz % per_p;
  const int band = q / (gx * 4), qq = q % (gx * 4);
  const int bx = qq >> 2, by = band * 4 + (qq & 3);

  const int tile_m = by * 256, tile_n = bx * 256;
  const bf16_t* Ab = A  + (int64_t)p * M  * KK + (int64_t)tile_m * KK;
  const bf16_t* Bb = Bt + (int64_t)p * NN * KK + (int64_t)tile_n * KK;
  const float* biasp = bias + (int64_t)p * NN;
  // per-thread B base: row = tile_n + wn*64 + fr (+n*16), k-elem base hi*8
  const bf16_t* const Bt_th = Bb + (int64_t)(wn * 64 + fr) * KK + hi * 8;

  f32x4 acc[8][4] = {};
  constexpr int NT = KK / 64;                  // K-tiles (even)

  bf16x8 a0[4][2], a1[4][2], b0[2][2], b1[2][2];

  // ---- prologue: stage A(t0)->buf0; load B(t0) into regs; certify ----
  stage_half<KK>(Ab,                       At0,          t);
  stage_half<KK>(Ab + (int64_t)128 * KK,   At0 + 16384,  t);
  LOAD_B(b0, 0, 0);
  LOAD_B(b1, 0, 2);
  VMCNT0();
  BAR(); SBAR();

  #pragma unroll 2
  for (int ti = 0; ti < NT; ++ti) {
    const int c   = ti & 1;                  // this tile's A buffer
    const int kn  = (ti + 1) * 64;           // next tile's k0
    const bool nxt = (ti + 1 < NT);

    // stage A(t+1) -> other buffer (WAR-safe: its reads ended before t-1's barrier)
    if (nxt) { stage_half<KK>(Ab + kn,                     At0 + (c ^ 1) * 32768,         t);
               stage_half<KK>(Ab + (int64_t)128 * KK + kn, At0 + (c ^ 1) * 32768 + 16384, t); }
    SBAR();
    FRAG_A(a0, c, 0);
    PRIO(1); MFMA_QUAD(a0, b0, 0, 0); PRIO(0); SBAR();
    FRAG_A(a1, c, 4);
    PRIO(1); MFMA_QUAD(a1, b0, 4, 0); PRIO(0); SBAR();
    // b0 regs free (Q1,Q3 issued) -> reload with B(t+1)
    if (nxt) LOAD_B(b0, kn, 0);
    SBAR();
    PRIO(1); MFMA_QUAD(a0, b1, 0, 2); PRIO(0); SBAR();
    PRIO(1); MFMA_QUAD(a1, b1, 4, 2); PRIO(0);
    // b1 regs free (Q2,Q4 issued) -> reload with B(t+1)
    if (nxt) LOAD_B(b1, kn, 2);
    if (nxt) VMCNT8(); else VMCNT0();        // retire A-stage (oldest 4 of 12)
    SBAR(); BAR();
  }

  // ---- epilogue: C/D layout col=lane&15, row=(lane>>4)*4+j ----
  float bv[4];
  #pragma unroll
  for (int n = 0; n < 4; ++n) bv[n] = biasp[tile_n + wn * 64 + n * 16 + fr];
  if (OUT_BF16) {
    bf16_t* out = (bf16_t*)outv + (int64_t)p * M * NN;
    #pragma unroll
    for (int m = 0; m < 8; ++m)
      #pragma unroll
      for (int j2 = 0; j2 < 4; ++j2) {
        const int row = tile_m + wm * 128 + m * 16 + hi * 4 + j2;
        #pragma unroll
        for (int n = 0; n < 4; ++n) {
          const int col = tile_n + wn * 64 + n * 16 + fr;
          float v = acc[m][n][j2] + bv[n];
          if (RELU) v = fmaxf(v, 0.0f);
          out[(int64_t)row * NN + col] = (bf16_t)v;
        }
      }
  } else {
    float* out = (float*)outv;
    #pragma unroll
    for (int m = 0; m < 8; ++m)
      #pragma unroll
      for (int j2 = 0; j2 < 4; ++j2) {
        const int row = tile_m + wm * 128 + m * 16 + hi * 4 + j2;
        const int grow = ((row >> 8) << 10) + p * SPP + (row & 255);
        #pragma unroll
        for (int n = 0; n < 4; ++n) {
          const int col = tile_n + wn * 64 + n * 16 + fr;
          out[(int64_t)grow * NN + col] = acc[m][n][j2] + bv[n];
        }
      }
  }
}

extern "C" void kernel_launch(void* const* d_in, const int* in_sizes, int n_in,
                              void* d_out, int out_size, void* d_ws, size_t ws_size,
                              hipStream_t stream) {
  (void)in_sizes; (void)n_in; (void)out_size; (void)ws_size;
  const float* x  = (const float*)d_in[0];
  const float* W1 = (const float*)d_in[1];
  const float* b1 = (const float*)d_in[2];
  const float* W2 = (const float*)d_in[3];
  const float* b2 = (const float*)d_in[4];
  // d_in[5] = phases: unused — static contiguous equal partition (reshape).
  float* y = (float*)d_out;

  char* ws = (char*)d_ws;
  bf16_t* xg = (bf16_t*)ws;                                   // 64 MiB  [P][8192][1024] bf16
  bf16_t* wt = (bf16_t*)(ws + (size_t)64 * 1024 * 1024);      // 32 MiB  [N][K] bf16 (W1t then W2t)
  bf16_t* h  = (bf16_t*)(ws + (size_t)96 * 1024 * 1024);      // 256 MiB [P][8192][4096] bf16

  conv_x_kernel<<<2048, 256, 0, stream>>>(x, xg);
  conv_wt_kernel<<<dim3(F_ / 32, D_ / 32, P_), 256, 0, stream>>>(W1, wt, D_, F_);
  ffgemm8_kernel<true, true, 1024, 4096><<<dim3(F_ / 256, MP / 256, P_), 512, 0, stream>>>(
      xg, wt, b1, h, MP);
  conv_wt_kernel<<<dim3(D_ / 32, F_ / 32, P_), 256, 0, stream>>>(W2, wt, F_, D_);
  ffgemm8_kernel<false, false, 4096, 1024><<<dim3(D_ / 256, MP / 256, P_), 512, 0, stream>>>(
      h, wt, b2, y, MP);
}

// Round 13
// 621.299 us; speedup vs baseline: 1.2509x; 1.2509x over previous
//
#include <hip/hip_runtime.h>
#include <hip/hip_bf16.h>
#include <stdint.h>

typedef __bf16 bf16_t;
typedef bf16_t bf16x8 __attribute__((ext_vector_type(8)));
typedef bf16_t bf16x4 __attribute__((ext_vector_type(4)));
typedef float  f32x16 __attribute__((ext_vector_type(16)));

#define AS1(p) ((const __attribute__((address_space(1))) void*)(p))
#define AS3(p) ((__attribute__((address_space(3))) void*)(p))

static constexpr int B_ = 32, S_ = 1024, D_ = 1024, P_ = 4, F_ = 4096;
static constexpr int SPP = S_ / P_;          // 256 rows per (batch, phase) chunk
static constexpr int MP  = B_ * SPP;         // 8192 rows per phase-group

// ---- x: [B,S,D] f32 -> xg: [P][MP][D] bf16 (phase-grouped, contiguous) ----
__global__ void conv_x_kernel(const float* __restrict__ x, bf16_t* __restrict__ xg) {
  const int64_t n4 = (int64_t)B_ * S_ * D_ / 4;
  for (int64_t i = (int64_t)blockIdx.x * blockDim.x + threadIdx.x; i < n4;
       i += (int64_t)gridDim.x * blockDim.x) {
    int64_t e = i << 2;
    int d = (int)(e & (D_ - 1));
    int s = (int)((e >> 10) & (S_ - 1));
    int b = (int)(e >> 20);
    int p = s >> 8;
    int r = (b << 8) | (s & 255);
    const float4 v = ((const float4*)x)[i];
    bf16x4 o;
    o[0] = (bf16_t)v.x; o[1] = (bf16_t)v.y; o[2] = (bf16_t)v.z; o[3] = (bf16_t)v.w;
    *(bf16x4*)&xg[(((int64_t)p * MP + r) << 10) | d] = o;
  }
}

// ---- W: [P][K][N] f32 -> Wt: [P][N][K] bf16 (LDS-tiled transpose) ----
__global__ void conv_wt_kernel(const float* __restrict__ W, bf16_t* __restrict__ Wt,
                               int K, int N) {
  __shared__ bf16_t tile[32][33];
  const int p = blockIdx.z;
  const float* Wp = W + (int64_t)p * K * N;
  bf16_t* Wtp = Wt + (int64_t)p * K * N;
  const int n0 = blockIdx.x * 32, k0 = blockIdx.y * 32;
  const int tx = threadIdx.x & 31, ty = threadIdx.x >> 5;
  #pragma unroll
  for (int j = 0; j < 4; ++j) {
    int kr = ty + j * 8;
    tile[kr][tx] = (bf16_t)Wp[(int64_t)(k0 + kr) * N + n0 + tx];
  }
  __syncthreads();
  #pragma unroll
  for (int j = 0; j < 4; ++j) {
    int nr = ty + j * 8;
    Wtp[(int64_t)(n0 + nr) * K + k0 + tx] = tile[tx][nr];
  }
}

// ====== 256x256 GEMM — R7 skeleton, 32x32x16 MFMA compute (R13) ======
// C[M,N] = A[M,K] * Bt[N,K]^T (+bias, opt ReLU). BM=BN=256, BK=64, 8 waves
// (2M x 4N; per-wave 128x64 as 4x2 blocks of 32x32).
// LDS 128 KiB: At0 At1 Bs0 Bs1 (256x64 bf16; halves = rows 0-127/128-255).
// Swizzle: (row,cb) at row*128 + (cb ^ ((row&7)<<4)); gload_lds dest LINEAR,
// inverse perm on global source (unchanged).
// MFMA 32x32x16: A frag row=lane&31, k-slice (lane>>5)*8 (byte hk*16);
// C/D: col=lane&31, row=(r&3)+8*(r>>2)+4*(lane>>5)  [m74/m101 verified].
// Per K-tile per wave: 32 MFMAs in 4 groups of 8; 24 ds_read_b128 placed
// 12/4/8/0 across the 4 phases (G2/G4 operands read one phase early).
// Barrier/stage/vmcnt structure BIT-IDENTICAL to R7 (552us best):
//   phA: reads(12) | G1(mh01,s01) | stage A1(t+1)   | SBAR BAR
//   phB: reads(4)  | G2(mh01,s23)                   | SBAR BAR
//   phC: reads(8)  | G3(mh23,s01) | stage B-pair(t+2)| SBAR BAR
//   phD:           | G4(mh23,s23) | stage A0(t+2) | VMCNT6/0 | SBAR BAR

__device__ __forceinline__ bf16x8 ldsX(const char* region, int row, int kb) {
  return *(const bf16x8*)(region + row * 128 + (kb ^ ((row & 7) << 4)));
}

template<int LDK>
__device__ __forceinline__ void stage_half(const bf16_t* gsrc, char* ldsreg, int t) {
  #pragma unroll
  for (int j = 0; j < 2; ++j) {
    const int idx = j * 512 + t;          // 1024 x 16B = 128 rows x 64 cols bf16
    const int row = idx >> 3;
    const int cb  = ((idx & 7) << 4) ^ ((row & 7) << 4);   // inverse-swizzled src col
    __builtin_amdgcn_global_load_lds(AS1((const char*)(gsrc + (int64_t)row * LDK) + cb),
                                     AS3(ldsreg + idx * 16), 16, 0, 0);
  }
}

#define MFMA32(A_, B_, C_) __builtin_amdgcn_mfma_f32_32x32x16_bf16(A_, B_, C_, 0, 0, 0)

// group of 8 MFMAs: m-halves MH0..MH0+1, k-slices S0..S0+1, both n-blocks
#define GRP(S0, MH0) \
  do { _Pragma("unroll") for (int s_ = (S0); s_ < (S0) + 2; ++s_) \
       _Pragma("unroll") for (int mh_ = (MH0); mh_ < (MH0) + 2; ++mh_) \
       _Pragma("unroll") for (int nh_ = 0; nh_ < 2; ++nh_) \
         acc[mh_][nh_] = MFMA32(af[mh_][s_], bf[nh_][s_], acc[mh_][nh_]); } while (0)

// A-frag reads for m-half MH, k-slices S0..S0+1
#define RD_A(REG, MH, S0) \
  do { _Pragma("unroll") for (int s_ = (S0); s_ < (S0) + 2; ++s_) \
         af[MH][s_] = ldsX(REG, wm * 128 + (MH) * 32 + l31, s_ * 32 + hk16); } while (0)

// B-frag reads for k-slices S0..S0+1, both n-blocks
#define RD_B(REG, S0) \
  do { _Pragma("unroll") for (int nh_ = 0; nh_ < 2; ++nh_) \
       _Pragma("unroll") for (int s_ = (S0); s_ < (S0) + 2; ++s_) \
         bf[nh_][s_] = ldsX(REG, wn * 64 + nh_ * 32 + l31, s_ * 32 + hk16); } while (0)

#define BAR()   __builtin_amdgcn_s_barrier()
#define SBAR()  __builtin_amdgcn_sched_barrier(0)
#define PRIO(x) __builtin_amdgcn_s_setprio(x)
#define VMCNT6() asm volatile("s_waitcnt vmcnt(6)" ::: "memory")
#define VMCNT0() asm volatile("s_waitcnt vmcnt(0)" ::: "memory")

template<bool RELU, bool OUT_BF16, int KK, int NN>
__global__ __launch_bounds__(512, 2)
void ffgemm8_kernel(const bf16_t* __restrict__ A, const bf16_t* __restrict__ Bt,
                    const float* __restrict__ bias, void* __restrict__ outv, int M) {
  static_assert(KK % 128 == 0, "need even number of 64-wide K tiles");
  __shared__ __align__(16) char smem[131072];
  char* const At0 = smem;
  char* const At1 = smem + 32768;
  char* const Bs0 = smem + 65536;
  char* const Bs1 = smem + 98304;

  const int t = threadIdx.x, lane = t & 63, w = t >> 6;
  const int wm = w >> 2, wn = w & 3;          // 2M x 4N wave grid
  const int l31 = lane & 31, hk = lane >> 5, hk16 = hk * 16;

  // T1: bijective XCD swizzle (nwg % 8 == 0) + 4-row supertile banding for L2
  const int gx = gridDim.x, gy = gridDim.y;
  const int nwg = gx * gy * (int)gridDim.z;
  const int id  = ((int)blockIdx.z * gy + (int)blockIdx.y) * gx + (int)blockIdx.x;
  const int swz = (id & 7) * (nwg >> 3) + (id >> 3);
  const int per_p = gx * gy;
  const int p  = swz / per_p;
  const int q  = swz % per_p;
  const int band = q / (gx * 4), qq = q % (gx * 4);
  const int bx = qq >> 2, by = band * 4 + (qq & 3);

  const int tile_m = by * 256, tile_n = bx * 256;
  const bf16_t* Ab = A  + (int64_t)p * M  * KK + (int64_t)tile_m * KK;
  const bf16_t* Bb = Bt + (int64_t)p * NN * KK + (int64_t)tile_n * KK;
  const float* biasp = bias + (int64_t)p * NN;

  f32x16 acc[4][2] = {};                      // [m-half 32][n-half 32]
  constexpr int NI = KK / 128;

  // ---- prologue: tile0 (A0,A1,B0,B1) -> buf0; tile1 (B0,B1,A0) -> buf1 ----
  stage_half<KK>(Ab,                          At0,          t);
  stage_half<KK>(Ab + (int64_t)128 * KK,      At0 + 16384,  t);
  stage_half<KK>(Bb,                          Bs0,          t);
  stage_half<KK>(Bb + (int64_t)128 * KK,      Bs0 + 16384,  t);
  stage_half<KK>(Bb + 64,                     Bs1,          t);
  stage_half<KK>(Bb + (int64_t)128 * KK + 64, Bs1 + 16384,  t);
  stage_half<KK>(Ab + 64,                     At1,          t);
  VMCNT6();          // retire tile0's 8 loads; tile1's B0,B1,A0 (6) in flight
  BAR(); SBAR();

  for (int i = 0; i < NI; ++i) {
    const int k0 = i * 128;                  // tile 2i @ k0, tile 2i+1 @ k0+64
    const bool more = (i < NI - 1);
    bf16x8 af[4][4], bf[2][4];

    // ===== half X: tile 2i from buf0 =====
    // phA: reads G1 set (8) + G2's A (4) | G1 | stage At1b: A1(t2i+1)
    RD_A(At0, 0, 0); RD_A(At0, 1, 0); RD_B(Bs0, 0);
    RD_A(At0, 0, 2); RD_A(At0, 1, 2);
    PRIO(1); GRP(0, 0); PRIO(0);
    stage_half<KK>(Ab + (int64_t)128 * KK + (k0 + 64), At1 + 16384, t);
    SBAR(); BAR();
    // phB: reads B s23 (4) | G2
    RD_B(Bs0, 2);
    PRIO(1); GRP(2, 0); PRIO(0);
    SBAR(); BAR();
    // phC: reads A mh23 (8) | G3 | stage Bs0: B0,B1(t2i+2)
    RD_A(At0, 2, 0); RD_A(At0, 3, 0); RD_A(At0, 2, 2); RD_A(At0, 3, 2);
    PRIO(1); GRP(0, 2); PRIO(0);
    if (more) { stage_half<KK>(Bb + (k0 + 128), Bs0, t);
                stage_half<KK>(Bb + (int64_t)128 * KK + (k0 + 128), Bs0 + 16384, t); }
    SBAR(); BAR();
    // phD: G4 | stage At0a: A0(t2i+2) | vmcnt retires tile 2i+1
    PRIO(1); GRP(2, 2); PRIO(0);
    if (more) stage_half<KK>(Ab + (k0 + 128), At0, t);
    if (more) VMCNT6(); else VMCNT0();
    SBAR(); BAR();

    // ===== half Y: tile 2i+1 from buf1 =====
    // phA': reads | G1' | stage At0b: A1(t2i+2)
    RD_A(At1, 0, 0); RD_A(At1, 1, 0); RD_B(Bs1, 0);
    RD_A(At1, 0, 2); RD_A(At1, 1, 2);
    PRIO(1); GRP(0, 0); PRIO(0);
    if (more) stage_half<KK>(Ab + (int64_t)128 * KK + (k0 + 128), At0 + 16384, t);
    SBAR(); BAR();
    // phB': reads B s23 | G2'
    RD_B(Bs1, 2);
    PRIO(1); GRP(2, 0); PRIO(0);
    SBAR(); BAR();
    // phC': reads A mh23 | G3' | stage Bs1: B0,B1(t2i+3)
    RD_A(At1, 2, 0); RD_A(At1, 3, 0); RD_A(At1, 2, 2); RD_A(At1, 3, 2);
    PRIO(1); GRP(0, 2); PRIO(0);
    if (more) { stage_half<KK>(Bb + (k0 + 192), Bs1, t);
                stage_half<KK>(Bb + (int64_t)128 * KK + (k0 + 192), Bs1 + 16384, t); }
    SBAR(); BAR();
    // phD': G4' | stage At1a: A0(t2i+3) | vmcnt retires tile 2i+2
    PRIO(1); GRP(2, 2); PRIO(0);
    if (more) stage_half<KK>(Ab + (k0 + 192), At1, t);
    if (more) VMCNT6(); else VMCNT0();
    SBAR(); BAR();
  }

  // ---- epilogue: 32x32 C/D layout col=lane&31, row=(r&3)+8*(r>>2)+4*hk ----
  float bv[2];
  #pragma unroll
  for (int nh = 0; nh < 2; ++nh) bv[nh] = biasp[tile_n + wn * 64 + nh * 32 + l31];
  if (OUT_BF16) {
    bf16_t* out = (bf16_t*)outv + (int64_t)p * M * NN;
    #pragma unroll
    for (int mh = 0; mh < 4; ++mh)
      #pragma unroll
      for (int r = 0; r < 16; ++r) {
        const int row = tile_m + wm * 128 + mh * 32 + (r & 3) + 8 * (r >> 2) + 4 * hk;
        #pragma unroll
        for (int nh = 0; nh < 2; ++nh) {
          const int col = tile_n + wn * 64 + nh * 32 + l31;
          float v = acc[mh][nh][r] + bv[nh];
          if (RELU) v = fmaxf(v, 0.0f);
          out[(int64_t)row * NN + col] = (bf16_t)v;
        }
      }
  } else {
    float* out = (float*)outv;
    #pragma unroll
    for (int mh = 0; mh < 4; ++mh)
      #pragma unroll
      for (int r = 0; r < 16; ++r) {
        const int row = tile_m + wm * 128 + mh * 32 + (r & 3) + 8 * (r >> 2) + 4 * hk;
        const int grow = ((row >> 8) << 10) + p * SPP + (row & 255);
        #pragma unroll
        for (int nh = 0; nh < 2; ++nh) {
          const int col = tile_n + wn * 64 + nh * 32 + l31;
          out[(int64_t)grow * NN + col] = acc[mh][nh][r] + bv[nh];
        }
      }
  }
}

extern "C" void kernel_launch(void* const* d_in, const int* in_sizes, int n_in,
                              void* d_out, int out_size, void* d_ws, size_t ws_size,
                              hipStream_t stream) {
  (void)in_sizes; (void)n_in; (void)out_size; (void)ws_size;
  const float* x  = (const float*)d_in[0];
  const float* W1 = (const float*)d_in[1];
  const float* b1 = (const float*)d_in[2];
  const float* W2 = (const float*)d_in[3];
  const float* b2 = (const float*)d_in[4];
  // d_in[5] = phases: unused — static contiguous equal partition (reshape).
  float* y = (float*)d_out;

  char* ws = (char*)d_ws;
  bf16_t* xg = (bf16_t*)ws;                                   // 64 MiB  [P][8192][1024] bf16
  bf16_t* wt = (bf16_t*)(ws + (size_t)64 * 1024 * 1024);      // 32 MiB  [N][K] bf16 (W1t then W2t)
  bf16_t* h  = (bf16_t*)(ws + (size_t)96 * 1024 * 1024);      // 256 MiB [P][8192][4096] bf16

  conv_x_kernel<<<2048, 256, 0, stream>>>(x, xg);
  conv_wt_kernel<<<dim3(F_ / 32, D_ / 32, P_), 256, 0, stream>>>(W1, wt, D_, F_);
  ffgemm8_kernel<true, true, 1024, 4096><<<dim3(F_ / 256, MP / 256, P_), 512, 0, stream>>>(
      xg, wt, b1, h, MP);
  conv_wt_kernel<<<dim3(D_ / 32, F_ / 32, P_), 256, 0, stream>>>(W2, wt, F_, D_);
  ffgemm8_kernel<false, false, 4096, 1024><<<dim3(D_ / 256, MP / 256, P_), 512, 0, stream>>>(
      h, wt, b2, y, MP);
}

// Round 14
// 570.533 us; speedup vs baseline: 1.3622x; 1.0890x over previous
//
#include <hip/hip_runtime.h>
#include <hip/hip_bf16.h>
#include <stdint.h>

typedef __bf16 bf16_t;
typedef bf16_t bf16x8 __attribute__((ext_vector_type(8)));
typedef bf16_t bf16x4 __attribute__((ext_vector_type(4)));
typedef float  f32x4  __attribute__((ext_vector_type(4)));

#define AS1(p) ((const __attribute__((address_space(1))) void*)(p))
#define AS3(p) ((__attribute__((address_space(3))) void*)(p))

static constexpr int B_ = 32, S_ = 1024, D_ = 1024, P_ = 4, F_ = 4096;
static constexpr int SPP = S_ / P_;          // 256 rows per (batch, phase) chunk
static constexpr int MP  = B_ * SPP;         // 8192 rows per phase-group

// ---- x: [B,S,D] f32 -> xg: [P][MP][D] bf16 (phase-grouped, contiguous) ----
__global__ void conv_x_kernel(const float* __restrict__ x, bf16_t* __restrict__ xg) {
  const int64_t n4 = (int64_t)B_ * S_ * D_ / 4;
  for (int64_t i = (int64_t)blockIdx.x * blockDim.x + threadIdx.x; i < n4;
       i += (int64_t)gridDim.x * blockDim.x) {
    int64_t e = i << 2;
    int d = (int)(e & (D_ - 1));
    int s = (int)((e >> 10) & (S_ - 1));
    int b = (int)(e >> 20);
    int p = s >> 8;
    int r = (b << 8) | (s & 255);
    const float4 v = ((const float4*)x)[i];
    bf16x4 o;
    o[0] = (bf16_t)v.x; o[1] = (bf16_t)v.y; o[2] = (bf16_t)v.z; o[3] = (bf16_t)v.w;
    *(bf16x4*)&xg[(((int64_t)p * MP + r) << 10) | d] = o;
  }
}

// ---- W: [P][K][N] f32 -> Wt: [P][N][K] bf16 (LDS-tiled transpose) ----
__global__ void conv_wt_kernel(const float* __restrict__ W, bf16_t* __restrict__ Wt,
                               int K, int N) {
  __shared__ bf16_t tile[32][33];
  const int p = blockIdx.z;
  const float* Wp = W + (int64_t)p * K * N;
  bf16_t* Wtp = Wt + (int64_t)p * K * N;
  const int n0 = blockIdx.x * 32, k0 = blockIdx.y * 32;
  const int tx = threadIdx.x & 31, ty = threadIdx.x >> 5;
  #pragma unroll
  for (int j = 0; j < 4; ++j) {
    int kr = ty + j * 8;
    tile[kr][tx] = (bf16_t)Wp[(int64_t)(k0 + kr) * N + n0 + tx];
  }
  __syncthreads();
  #pragma unroll
  for (int j = 0; j < 4; ++j) {
    int nr = ty + j * 8;
    Wtp[(int64_t)(n0 + nr) * K + k0 + tx] = tile[tx][nr];
  }
}

// ====== 256x256 GEMM, fully read-ahead pipeline, spill-free carry (R14) ======
// C[M,N] = A[M,K] * Bt[N,K]^T (+bias, opt ReLU). BM=BN=256, BK=64, 8 waves.
// LDS 128 KiB: At0 At1 Bs0 Bs1 (256x64 bf16; halves a/b = rows 0-127/128-255).
// Swizzle: (row, cb) at row*128 + (cb ^ ((row&7)<<4)); gload_lds dest LINEAR,
// inverse perm on the global source. 16x16x32 MFMA (conflict-free pattern).
//
// R14 = R8's schedule with ONLY a0,b0 loop-carried (48 VGPR; back-edge live
// ~78, peak ~124 = R7's count). R8 carried all four (96) -> spill -> its
// regression. Schedule per half (reads one phase ahead of their wait):
//   phA: Q1(a0,b0) | read b1 | stage A1(t+1)               | SBAR BAR
//   phB: Q2(a0,b1) | read a1                               | SBAR BAR
//   phC: Q3(a1,b0) | stage B-pair(t+2) | VMCNT4/0 certify  | SBAR BAR
//   phD: Q4(a1,b1) | stage A0(t+2) | pre-read NEXT a0,b0   | SBAR BAR
// FIFO at phC (after B-pair issue), oldest->newest:
//   [B01(t+1):4? retired earlier] ... loads since prev vmcnt: A0(t+1):2 @prev
//   phD, A1(t+1):2 @phA, B01(t+2):4 @phC  -> vmcnt(4) retires through
//   A1(t+1) = tile t+1 complete; phD pre-reads of t+1 are RAW-safe (+BAR).
// WAR (all verified, >=1 barrier after overwritten region's last waited read):
//   A1->At1b @phA: At1b reads (prev a0-pre@phD, a1@phB') waited by Q3' < bar.
//   B01->Bs0 @phC: b0 waited@Q1(phA), b1 waited@Q2(phB) < phB bar.
//   A0->At0a @phD: a0 waited@Q1, a1 waited@Q3 < phC bar.

__device__ __forceinline__ bf16x8 ldsfrag(const char* region, int row, int cb) {
  return *(const bf16x8*)(region + row * 128 + (cb ^ ((row & 7) << 4)));
}

template<int LDK>
__device__ __forceinline__ void stage_half(const bf16_t* gsrc, char* ldsreg, int t) {
  #pragma unroll
  for (int j = 0; j < 2; ++j) {
    const int idx = j * 512 + t;          // 1024 x 16B = 128 rows x 64 cols bf16
    const int row = idx >> 3;
    const int cb  = ((idx & 7) << 4) ^ ((row & 7) << 4);   // inverse-swizzled src col
    __builtin_amdgcn_global_load_lds(AS1((const char*)(gsrc + (int64_t)row * LDK) + cb),
                                     AS3(ldsreg + idx * 16), 16, 0, 0);
  }
}

#define MFMA_QUAD(AF, BF, MO, NO) \
  do { _Pragma("unroll") for (int m_ = 0; m_ < 4; ++m_) \
       _Pragma("unroll") for (int n_ = 0; n_ < 2; ++n_) \
       _Pragma("unroll") for (int k_ = 0; k_ < 2; ++k_) \
         acc[(MO) + m_][(NO) + n_] = __builtin_amdgcn_mfma_f32_16x16x32_bf16( \
             AF[m_][k_], BF[n_][k_], acc[(MO) + m_][(NO) + n_], 0, 0, 0); } while (0)

#define READ_A4(DST, REG, MO) \
  do { _Pragma("unroll") for (int m_ = 0; m_ < 4; ++m_) \
       _Pragma("unroll") for (int k_ = 0; k_ < 2; ++k_) \
         DST[m_][k_] = ldsfrag(REG, wm * 128 + ((MO) + m_) * 16 + fr, k_ * 64 + hi * 16); } while (0)

#define READ_B2(DST, REG, NO) \
  do { _Pragma("unroll") for (int n_ = 0; n_ < 2; ++n_) \
       _Pragma("unroll") for (int k_ = 0; k_ < 2; ++k_) \
         DST[n_][k_] = ldsfrag(REG, wn * 64 + ((NO) + n_) * 16 + fr, k_ * 64 + hi * 16); } while (0)

#define BAR()   __builtin_amdgcn_s_barrier()
#define SBAR()  __builtin_amdgcn_sched_barrier(0)
#define PRIO(x) __builtin_amdgcn_s_setprio(x)
#define VMCNT6() asm volatile("s_waitcnt vmcnt(6)" ::: "memory")
#define VMCNT4() asm volatile("s_waitcnt vmcnt(4)" ::: "memory")
#define VMCNT0() asm volatile("s_waitcnt vmcnt(0)" ::: "memory")

template<bool RELU, bool OUT_BF16, int KK, int NN>
__global__ __launch_bounds__(512, 2)
void ffgemm8_kernel(const bf16_t* __restrict__ A, const bf16_t* __restrict__ Bt,
                    const float* __restrict__ bias, void* __restrict__ outv, int M) {
  static_assert(KK % 128 == 0, "need even number of 64-wide K tiles");
  __shared__ __align__(16) char smem[131072];
  char* const At0 = smem;
  char* const At1 = smem + 32768;
  char* const Bs0 = smem + 65536;
  char* const Bs1 = smem + 98304;

  const int t = threadIdx.x, lane = t & 63, w = t >> 6;
  const int wm = w >> 2, wn = w & 3;          // 2M x 4N wave grid
  const int fr = lane & 15, hi = lane >> 4;

  // T1: bijective XCD swizzle (nwg % 8 == 0) + 4-row supertile banding for L2
  const int gx = gridDim.x, gy = gridDim.y;
  const int nwg = gx * gy * (int)gridDim.z;
  const int id  = ((int)blockIdx.z * gy + (int)blockIdx.y) * gx + (int)blockIdx.x;
  const int swz = (id & 7) * (nwg >> 3) + (id >> 3);
  const int per_p = gx * gy;
  const int p  = swz / per_p;
  const int q  = swz % per_p;
  const int band = q / (gx * 4), qq = q % (gx * 4);
  const int bx = qq >> 2, by = band * 4 + (qq & 3);

  const int tile_m = by * 256, tile_n = bx * 256;
  const bf16_t* Ab = A  + (int64_t)p * M  * KK + (int64_t)tile_m * KK;
  const bf16_t* Bb = Bt + (int64_t)p * NN * KK + (int64_t)tile_n * KK;
  const float* biasp = bias + (int64_t)p * NN;

  f32x4 acc[8][4] = {};
  constexpr int NI = KK / 128;

  bf16x8 a0[4][2], b0[2][2];                   // ONLY these are loop-carried

  // ---- prologue: tile0 (A0,A1,B0,B1) -> buf0; tile1 (B0,B1,A0) -> buf1 ----
  stage_half<KK>(Ab,                          At0,          t);
  stage_half<KK>(Ab + (int64_t)128 * KK,      At0 + 16384,  t);
  stage_half<KK>(Bb,                          Bs0,          t);
  stage_half<KK>(Bb + (int64_t)128 * KK,      Bs0 + 16384,  t);
  stage_half<KK>(Bb + 64,                     Bs1,          t);
  stage_half<KK>(Bb + (int64_t)128 * KK + 64, Bs1 + 16384,  t);
  stage_half<KK>(Ab + 64,                     At1,          t);
  VMCNT6();          // retire tile0's 8 loads; tile1's B0,B1,A0 (6) in flight
  BAR(); SBAR();
  READ_A4(a0, At0, 0); READ_B2(b0, Bs0, 0);   // pre-read tile0's Q1 operands

  for (int i = 0; i < NI; ++i) {
    const int k0 = i * 128;                  // tile 2i @ k0, tile 2i+1 @ k0+64
    const bool more = (i < NI - 1);
    bf16x8 a1[4][2], b1[2][2];               // intra-iteration only

    // ===== half X: tile 2i from buf0 =====
    // phA: Q1 (operands read in prev phD) | read b1 | stage At1b: A1(t2i+1)
    PRIO(1); MFMA_QUAD(a0, b0, 0, 0); PRIO(0);
    READ_B2(b1, Bs0, 2);
    stage_half<KK>(Ab + (int64_t)128 * KK + (k0 + 64), At1 + 16384, t);
    SBAR(); BAR();
    // phB: Q2 | read a1
    PRIO(1); MFMA_QUAD(a0, b1, 0, 2); PRIO(0);
    READ_A4(a1, At0, 4);
    SBAR(); BAR();
    // phC: Q3 | stage Bs0: B0,B1(t2i+2) | certify tile 2i+1
    PRIO(1); MFMA_QUAD(a1, b0, 4, 0); PRIO(0);
    if (more) { stage_half<KK>(Bb + (k0 + 128), Bs0, t);
                stage_half<KK>(Bb + (int64_t)128 * KK + (k0 + 128), Bs0 + 16384, t); }
    if (more) VMCNT4(); else VMCNT0();
    SBAR(); BAR();
    // phD: Q4 | stage At0a: A0(t2i+2) | pre-read half-Y Q1 operands
    PRIO(1); MFMA_QUAD(a1, b1, 4, 2); PRIO(0);
    if (more) stage_half<KK>(Ab + (k0 + 128), At0, t);
    READ_A4(a0, At1, 0); READ_B2(b0, Bs1, 0);
    SBAR(); BAR();

    // ===== half Y: tile 2i+1 from buf1 =====
    // phA': Q1' | read b1' | stage At0b: A1(t2i+2)
    PRIO(1); MFMA_QUAD(a0, b0, 0, 0); PRIO(0);
    READ_B2(b1, Bs1, 2);
    if (more) stage_half<KK>(Ab + (int64_t)128 * KK + (k0 + 128), At0 + 16384, t);
    SBAR(); BAR();
    // phB': Q2' | read a1'
    PRIO(1); MFMA_QUAD(a0, b1, 0, 2); PRIO(0);
    READ_A4(a1, At1, 4);
    SBAR(); BAR();
    // phC': Q3' | stage Bs1: B0,B1(t2i+3) | certify tile 2i+2
    PRIO(1); MFMA_QUAD(a1, b0, 4, 0); PRIO(0);
    if (more) { stage_half<KK>(Bb + (k0 + 192), Bs1, t);
                stage_half<KK>(Bb + (int64_t)128 * KK + (k0 + 192), Bs1 + 16384, t); }
    if (more) VMCNT4(); else VMCNT0();
    SBAR(); BAR();
    // phD': Q4' | stage At1a: A0(t2i+3) | pre-read next half-X Q1 operands
    PRIO(1); MFMA_QUAD(a1, b1, 4, 2); PRIO(0);
    if (more) stage_half<KK>(Ab + (k0 + 192), At1, t);
    READ_A4(a0, At0, 0); READ_B2(b0, Bs0, 0);  // last iter: stale, unused
    SBAR(); BAR();
  }

  // ---- epilogue: C/D layout col=lane&15, row=(lane>>4)*4+j ----
  float bv[4];
  #pragma unroll
  for (int n = 0; n < 4; ++n) bv[n] = biasp[tile_n + wn * 64 + n * 16 + fr];
  if (OUT_BF16) {
    bf16_t* out = (bf16_t*)outv + (int64_t)p * M * NN;
    #pragma unroll
    for (int m = 0; m < 8; ++m)
      #pragma unroll
      for (int j = 0; j < 4; ++j) {
        const int row = tile_m + wm * 128 + m * 16 + hi * 4 + j;
        #pragma unroll
        for (int n = 0; n < 4; ++n) {
          const int col = tile_n + wn * 64 + n * 16 + fr;
          float v = acc[m][n][j] + bv[n];
          if (RELU) v = fmaxf(v, 0.0f);
          out[(int64_t)row * NN + col] = (bf16_t)v;
        }
      }
  } else {
    float* out = (float*)outv;
    #pragma unroll
    for (int m = 0; m < 8; ++m)
      #pragma unroll
      for (int j = 0; j < 4; ++j) {
        const int row = tile_m + wm * 128 + m * 16 + hi * 4 + j;
        const int grow = ((row >> 8) << 10) + p * SPP + (row & 255);
        #pragma unroll
        for (int n = 0; n < 4; ++n) {
          const int col = tile_n + wn * 64 + n * 16 + fr;
          out[(int64_t)grow * NN + col] = acc[m][n][j] + bv[n];
        }
      }
  }
}

extern "C" void kernel_launch(void* const* d_in, const int* in_sizes, int n_in,
                              void* d_out, int out_size, void* d_ws, size_t ws_size,
                              hipStream_t stream) {
  (void)in_sizes; (void)n_in; (void)out_size; (void)ws_size;
  const float* x  = (const float*)d_in[0];
  const float* W1 = (const float*)d_in[1];
  const float* b1 = (const float*)d_in[2];
  const float* W2 = (const float*)d_in[3];
  const float* b2 = (const float*)d_in[4];
  // d_in[5] = phases: unused — static contiguous equal partition (reshape).
  float* y = (float*)d_out;

  char* ws = (char*)d_ws;
  bf16_t* xg = (bf16_t*)ws;                                   // 64 MiB  [P][8192][1024] bf16
  bf16_t* wt = (bf16_t*)(ws + (size_t)64 * 1024 * 1024);      // 32 MiB  [N][K] bf16 (W1t then W2t)
  bf16_t* h  = (bf16_t*)(ws + (size_t)96 * 1024 * 1024);      // 256 MiB [P][8192][4096] bf16

  conv_x_kernel<<<2048, 256, 0, stream>>>(x, xg);
  conv_wt_kernel<<<dim3(F_ / 32, D_ / 32, P_), 256, 0, stream>>>(W1, wt, D_, F_);
  ffgemm8_kernel<true, true, 1024, 4096><<<dim3(F_ / 256, MP / 256, P_), 512, 0, stream>>>(
      xg, wt, b1, h, MP);
  conv_wt_kernel<<<dim3(D_ / 32, F_ / 32, P_), 256, 0, stream>>>(W2, wt, F_, D_);
  ffgemm8_kernel<false, false, 4096, 1024><<<dim3(D_ / 256, MP / 256, P_), 512, 0, stream>>>(
      h, wt, b2, y, MP);
}

// Round 15
// 568.048 us; speedup vs baseline: 1.3682x; 1.0044x over previous
//
#include <hip/hip_runtime.h>
#include <hip/hip_bf16.h>
#include <stdint.h>

typedef __bf16 bf16_t;
typedef bf16_t bf16x8 __attribute__((ext_vector_type(8)));
typedef bf16_t bf16x4 __attribute__((ext_vector_type(4)));
typedef float  f32x4  __attribute__((ext_vector_type(4)));

#define AS1(p) ((const __attribute__((address_space(1))) void*)(p))
#define AS3(p) ((__attribute__((address_space(3))) void*)(p))

static constexpr int B_ = 32, S_ = 1024, D_ = 1024, P_ = 4, F_ = 4096;
static constexpr int SPP = S_ / P_;          // 256 rows per (batch, phase) chunk
static constexpr int MP  = B_ * SPP;         // 8192 rows per phase-group

// ---- x: [B,S,D] f32 -> xg: [P][MP][D] bf16 (phase-grouped, contiguous) ----
__global__ void conv_x_kernel(const float* __restrict__ x, bf16_t* __restrict__ xg) {
  const int64_t n4 = (int64_t)B_ * S_ * D_ / 4;
  for (int64_t i = (int64_t)blockIdx.x * blockDim.x + threadIdx.x; i < n4;
       i += (int64_t)gridDim.x * blockDim.x) {
    int64_t e = i << 2;
    int d = (int)(e & (D_ - 1));
    int s = (int)((e >> 10) & (S_ - 1));
    int b = (int)(e >> 20);
    int p = s >> 8;
    int r = (b << 8) | (s & 255);
    const float4 v = ((const float4*)x)[i];
    bf16x4 o;
    o[0] = (bf16_t)v.x; o[1] = (bf16_t)v.y; o[2] = (bf16_t)v.z; o[3] = (bf16_t)v.w;
    *(bf16x4*)&xg[(((int64_t)p * MP + r) << 10) | d] = o;
  }
}

// ---- merged W1+W2 transpose: [P][K][N] f32 -> [P][N][K] bf16, 1D grid ----
// blocks 0 .. 16383: W1 (K=1024,N=4096); 16384 .. 32767: W2 (K=4096,N=1024)
__global__ void conv_wt2_kernel(const float* __restrict__ W1, bf16_t* __restrict__ W1t,
                                const float* __restrict__ W2, bf16_t* __restrict__ W2t) {
  __shared__ bf16_t tile[32][33];
  int bid = blockIdx.x;
  const float* W; bf16_t* Wt; int K, N;
  if (bid < 16384) { W = W1; Wt = W1t; K = D_; N = F_; }
  else             { W = W2; Wt = W2t; K = F_; N = D_; bid -= 16384; }
  // per-weight: 4096 tiles of 32x32 per phase-agnostic layout: decode p, nt, kt
  const int ntiles_n = N / 32, ntiles_k = K / 32;      // 128x32 or 32x128
  const int per_p = ntiles_n * ntiles_k;               // 4096
  const int p  = bid / per_p;
  const int q  = bid % per_p;
  const int nt = q % ntiles_n, kt = q / ntiles_n;
  const float* Wp = W + (int64_t)p * K * N;
  bf16_t* Wtp = Wt + (int64_t)p * K * N;
  const int n0 = nt * 32, k0 = kt * 32;
  const int tx = threadIdx.x & 31, ty = threadIdx.x >> 5;
  #pragma unroll
  for (int j = 0; j < 4; ++j) {
    int kr = ty + j * 8;
    tile[kr][tx] = (bf16_t)Wp[(int64_t)(k0 + kr) * N + n0 + tx];
  }
  __syncthreads();
  #pragma unroll
  for (int j = 0; j < 4; ++j) {
    int nr = ty + j * 8;
    Wtp[(int64_t)(n0 + nr) * K + k0 + tx] = tile[tx][nr];
  }
}

// ====== 256x256 GEMM, read-one-phase-ahead pipeline (R7 — best, final) ======
// C[M,N] = A[M,K] * Bt[N,K]^T (+bias, opt ReLU). BM=BN=256, BK=64, 8 waves.
// LDS 128 KiB: At0 At1 Bs0 Bs1 (256x64 bf16; halves a/b = rows 0-127/128-255).
// Swizzle: (row, cb) at row*128 + (cb ^ ((row&7)<<4)); gload_lds dest LINEAR,
// inverse perm on the global source (both-sides rule).
//
// Measured ceiling analysis (R2..R14): per K-tile per CU, MFMA 2483 cy and
// fragment-read traffic 192 KB (3x re-read amplification of the 2Mx4N wave
// grid) ~ 2304 cy serialize under barrier-locked phases; register budget
// (124 VGPR + 128 acc AGPR ~ 252/256) forbids cross-phase fragment carry
// (R8/R11/R14 all spilled), and wave de-phasing needs sub-workgroup barriers
// that plain HIP lacks. 43-49% MfmaUtil across 7 schedule variants; this
// (R7) is the best measured: 48.2%, 552us total.
//   phA: Q1(a0,b0 reads exposed) | read b1 | stage A1(t+1)   | SBAR BAR
//   phB: Q2 | read a1                                         | SBAR BAR
//   phC: Q3 | stage B-pair(t+2)                               | SBAR BAR
//   phD: Q4 | stage A0(t+2) | VMCNT6/0 (retire tile t+1)      | SBAR BAR

__device__ __forceinline__ bf16x8 ldsfrag(const char* region, int row, int cb) {
  return *(const bf16x8*)(region + row * 128 + (cb ^ ((row & 7) << 4)));
}

template<int LDK>
__device__ __forceinline__ void stage_half(const bf16_t* gsrc, char* ldsreg, int t) {
  #pragma unroll
  for (int j = 0; j < 2; ++j) {
    const int idx = j * 512 + t;          // 1024 x 16B = 128 rows x 64 cols bf16
    const int row = idx >> 3;
    const int cb  = ((idx & 7) << 4) ^ ((row & 7) << 4);   // inverse-swizzled src col
    __builtin_amdgcn_global_load_lds(AS1((const char*)(gsrc + (int64_t)row * LDK) + cb),
                                     AS3(ldsreg + idx * 16), 16, 0, 0);
  }
}

#define MFMA_QUAD(AF, BF, MO, NO) \
  do { _Pragma("unroll") for (int m_ = 0; m_ < 4; ++m_) \
       _Pragma("unroll") for (int n_ = 0; n_ < 2; ++n_) \
       _Pragma("unroll") for (int k_ = 0; k_ < 2; ++k_) \
         acc[(MO) + m_][(NO) + n_] = __builtin_amdgcn_mfma_f32_16x16x32_bf16( \
             AF[m_][k_], BF[n_][k_], acc[(MO) + m_][(NO) + n_], 0, 0, 0); } while (0)

#define READ_A4(DST, REG, MO) \
  do { _Pragma("unroll") for (int m_ = 0; m_ < 4; ++m_) \
       _Pragma("unroll") for (int k_ = 0; k_ < 2; ++k_) \
         DST[m_][k_] = ldsfrag(REG, wm * 128 + ((MO) + m_) * 16 + fr, k_ * 64 + hi * 16); } while (0)

#define READ_B2(DST, REG, NO) \
  do { _Pragma("unroll") for (int n_ = 0; n_ < 2; ++n_) \
       _Pragma("unroll") for (int k_ = 0; k_ < 2; ++k_) \
         DST[n_][k_] = ldsfrag(REG, wn * 64 + ((NO) + n_) * 16 + fr, k_ * 64 + hi * 16); } while (0)

#define BAR()   __builtin_amdgcn_s_barrier()
#define SBAR()  __builtin_amdgcn_sched_barrier(0)
#define PRIO(x) __builtin_amdgcn_s_setprio(x)
#define VMCNT6() asm volatile("s_waitcnt vmcnt(6)" ::: "memory")
#define VMCNT0() asm volatile("s_waitcnt vmcnt(0)" ::: "memory")

template<bool RELU, bool OUT_BF16, int KK, int NN>
__global__ __launch_bounds__(512, 2)
void ffgemm8_kernel(const bf16_t* __restrict__ A, const bf16_t* __restrict__ Bt,
                    const float* __restrict__ bias, void* __restrict__ outv, int M) {
  static_assert(KK % 128 == 0, "need even number of 64-wide K tiles");
  __shared__ __align__(16) char smem[131072];
  char* const At0 = smem;
  char* const At1 = smem + 32768;
  char* const Bs0 = smem + 65536;
  char* const Bs1 = smem + 98304;

  const int t = threadIdx.x, lane = t & 63, w = t >> 6;
  const int wm = w >> 2, wn = w & 3;          // 2M x 4N wave grid
  const int fr = lane & 15, hi = lane >> 4;

  // T1: bijective XCD swizzle (nwg % 8 == 0) + 4-row supertile banding for L2
  const int gx = gridDim.x, gy = gridDim.y;
  const int nwg = gx * gy * (int)gridDim.z;
  const int id  = ((int)blockIdx.z * gy + (int)blockIdx.y) * gx + (int)blockIdx.x;
  const int swz = (id & 7) * (nwg >> 3) + (id >> 3);
  const int per_p = gx * gy;
  const int p  = swz / per_p;
  const int q  = swz % per_p;
  const int band = q / (gx * 4), qq = q % (gx * 4);
  const int bx = qq >> 2, by = band * 4 + (qq & 3);

  const int tile_m = by * 256, tile_n = bx * 256;
  const bf16_t* Ab = A  + (int64_t)p * M  * KK + (int64_t)tile_m * KK;
  const bf16_t* Bb = Bt + (int64_t)p * NN * KK + (int64_t)tile_n * KK;
  const float* biasp = bias + (int64_t)p * NN;

  f32x4 acc[8][4] = {};
  constexpr int NI = KK / 128;

  // ---- prologue: tile0 (A0,A1,B0,B1) -> buf0; tile1 (B0,B1,A0) -> buf1 ----
  stage_half<KK>(Ab,                          At0,          t);
  stage_half<KK>(Ab + (int64_t)128 * KK,      At0 + 16384,  t);
  stage_half<KK>(Bb,                          Bs0,          t);
  stage_half<KK>(Bb + (int64_t)128 * KK,      Bs0 + 16384,  t);
  stage_half<KK>(Bb + 64,                     Bs1,          t);
  stage_half<KK>(Bb + (int64_t)128 * KK + 64, Bs1 + 16384,  t);
  stage_half<KK>(Ab + 64,                     At1,          t);
  VMCNT6();          // retire tile0's 8 loads; tile1's B0,B1,A0 (6) in flight
  BAR(); SBAR();

  for (int i = 0; i < NI; ++i) {
    const int k0 = i * 128;                  // tile 2i @ k0, tile 2i+1 @ k0+64
    const bool more = (i < NI - 1);
    bf16x8 a0[4][2], a1[4][2], b0[2][2], b1[2][2];

    // ===== half X: tile 2i from buf0 =====
    READ_A4(a0, At0, 0); READ_B2(b0, Bs0, 0);
    PRIO(1); MFMA_QUAD(a0, b0, 0, 0); PRIO(0);
    READ_B2(b1, Bs0, 2);
    stage_half<KK>(Ab + (int64_t)128 * KK + (k0 + 64), At1 + 16384, t);
    SBAR(); BAR();
    PRIO(1); MFMA_QUAD(a0, b1, 0, 2); PRIO(0);
    READ_A4(a1, At0, 4);
    SBAR(); BAR();
    PRIO(1); MFMA_QUAD(a1, b0, 4, 0); PRIO(0);
    if (more) { stage_half<KK>(Bb + (k0 + 128), Bs0, t);
                stage_half<KK>(Bb + (int64_t)128 * KK + (k0 + 128), Bs0 + 16384, t); }
    SBAR(); BAR();
    PRIO(1); MFMA_QUAD(a1, b1, 4, 2); PRIO(0);
    if (more) stage_half<KK>(Ab + (k0 + 128), At0, t);
    if (more) VMCNT6(); else VMCNT0();
    SBAR(); BAR();

    // ===== half Y: tile 2i+1 from buf1 =====
    READ_A4(a0, At1, 0); READ_B2(b0, Bs1, 0);
    PRIO(1); MFMA_QUAD(a0, b0, 0, 0); PRIO(0);
    READ_B2(b1, Bs1, 2);
    if (more) stage_half<KK>(Ab + (int64_t)128 * KK + (k0 + 128), At0 + 16384, t);
    SBAR(); BAR();
    PRIO(1); MFMA_QUAD(a0, b1, 0, 2); PRIO(0);
    READ_A4(a1, At1, 4);
    SBAR(); BAR();
    PRIO(1); MFMA_QUAD(a1, b0, 4, 0); PRIO(0);
    if (more) { stage_half<KK>(Bb + (k0 + 192), Bs1, t);
                stage_half<KK>(Bb + (int64_t)128 * KK + (k0 + 192), Bs1 + 16384, t); }
    SBAR(); BAR();
    PRIO(1); MFMA_QUAD(a1, b1, 4, 2); PRIO(0);
    if (more) stage_half<KK>(Ab + (k0 + 192), At1, t);
    if (more) VMCNT6(); else VMCNT0();
    SBAR(); BAR();
  }

  // ---- epilogue: C/D layout col=lane&15, row=(lane>>4)*4+j ----
  float bv[4];
  #pragma unroll
  for (int n = 0; n < 4; ++n) bv[n] = biasp[tile_n + wn * 64 + n * 16 + fr];
  if (OUT_BF16) {
    bf16_t* out = (bf16_t*)outv + (int64_t)p * M * NN;
    #pragma unroll
    for (int m = 0; m < 8; ++m)
      #pragma unroll
      for (int j = 0; j < 4; ++j) {
        const int row = tile_m + wm * 128 + m * 16 + hi * 4 + j;
        #pragma unroll
        for (int n = 0; n < 4; ++n) {
          const int col = tile_n + wn * 64 + n * 16 + fr;
          float v = acc[m][n][j] + bv[n];
          if (RELU) v = fmaxf(v, 0.0f);
          out[(int64_t)row * NN + col] = (bf16_t)v;
        }
      }
  } else {
    float* out = (float*)outv;
    #pragma unroll
    for (int m = 0; m < 8; ++m)
      #pragma unroll
      for (int j = 0; j < 4; ++j) {
        const int row = tile_m + wm * 128 + m * 16 + hi * 4 + j;
        const int grow = ((row >> 8) << 10) + p * SPP + (row & 255);
        #pragma unroll
        for (int n = 0; n < 4; ++n) {
          const int col = tile_n + wn * 64 + n * 16 + fr;
          out[(int64_t)grow * NN + col] = acc[m][n][j] + bv[n];
        }
      }
  }
}

extern "C" void kernel_launch(void* const* d_in, const int* in_sizes, int n_in,
                              void* d_out, int out_size, void* d_ws, size_t ws_size,
                              hipStream_t stream) {
  (void)in_sizes; (void)n_in; (void)out_size; (void)ws_size;
  const float* x  = (const float*)d_in[0];
  const float* W1 = (const float*)d_in[1];
  const float* b1 = (const float*)d_in[2];
  const float* W2 = (const float*)d_in[3];
  const float* b2 = (const float*)d_in[4];
  // d_in[5] = phases: unused — static contiguous equal partition (reshape).
  float* y = (float*)d_out;

  char* ws = (char*)d_ws;
  bf16_t* xg  = (bf16_t*)ws;                                   // 64 MiB [P][8192][1024]
  bf16_t* w1t = (bf16_t*)(ws + (size_t)64  * 1024 * 1024);     // 32 MiB [P][F][D] bf16
  bf16_t* w2t = (bf16_t*)(ws + (size_t)96  * 1024 * 1024);     // 32 MiB [P][D][F] bf16
  bf16_t* h   = (bf16_t*)(ws + (size_t)128 * 1024 * 1024);     // 256 MiB [P][8192][4096]
  // total ws use: 384 MiB

  conv_x_kernel<<<2048, 256, 0, stream>>>(x, xg);
  conv_wt2_kernel<<<32768, 256, 0, stream>>>(W1, w1t, W2, w2t);
  ffgemm8_kernel<true, true, 1024, 4096><<<dim3(F_ / 256, MP / 256, P_), 512, 0, stream>>>(
      xg, w1t, b1, h, MP);
  ffgemm8_kernel<false, false, 4096, 1024><<<dim3(D_ / 256, MP / 256, P_), 512, 0, stream>>>(
      h, w2t, b2, y, MP);
}